// Round 12
// baseline (244.604 us; speedup 1.0000x reference)
//
#include <hip/hip_runtime.h>

#define NF 64
#define ND 32
#define NPAIR 2016
#define SPW 2   // samples per wave; ALL loads issued before ANY store

typedef __attribute__((ext_vector_type(8))) short bf16x8;
typedef __attribute__((ext_vector_type(4))) float f32x4;

// R11 post-mortem: per-wave-per-sample time pinned at ~13 us across ALL
// structures (R10 1-sample waves and R11 4-sample pipelined waves alike).
// Theory: vmcnt is shared by loads+stores and retires oldest-first, so
// waiting for sample k+1's loads forces sample k-1's stores to COMPLETE
// (~10 us under 20 MB of in-flight writes). Fix: issue every global load
// (both samples) before any global store; stores are then never waited on
// except one endpgm drain per 2 samples. No LDS (occupancy-free, no lgkm
// round-trip); direct scattered stores (R5-validated: +8% writes, L2 merges).
__global__ __launch_bounds__(256, 4) void ip_gram_mfma(
    const float* __restrict__ in, float* __restrict__ out) {

    const int t = threadIdx.x;
    const int w = t >> 6;
    const int l = t & 63;
    const int g = blockIdx.x * 4 + w;     // 2048 blocks * 4 waves = 8192 waves
    const int s0 = g * SPW;

    const int q = l >> 4;                 // k-block: lane covers k = 8q..8q+7
    const int m = l & 15;                 // row within each 16-row block

    const float* src0 = in + (size_t)s0 * (NF * ND) + (q << 3);

    // ---- ALL global loads first: 16 dwordx4, two samples' fragments ----
    float4 bufA[8], bufB[8];              // [2r] = row half0, [2r+1] = half1
    #pragma unroll
    for (int r = 0; r < 4; ++r) {
        const float* rowp = src0 + (r * 16 + m) * ND;
        bufA[2 * r]     = ((const float4*)rowp)[0];
        bufA[2 * r + 1] = ((const float4*)rowp)[1];
    }
    #pragma unroll
    for (int r = 0; r < 4; ++r) {
        const float* rowp = src0 + NF * ND + (r * 16 + m) * ND;
        bufB[2 * r]     = ((const float4*)rowp)[0];
        bufB[2 * r + 1] = ((const float4*)rowp)[1];
    }

    auto PROCESS = [&](const float4* buf, int k) {
        // fp32 -> bf16 hi/lo split (exact residual) — R5-validated numerics
        bf16x8 fhi[4], flo[4];
        #pragma unroll
        for (int r = 0; r < 4; ++r) {
            float xv[8] = {buf[2*r].x, buf[2*r].y, buf[2*r].z, buf[2*r].w,
                           buf[2*r+1].x, buf[2*r+1].y, buf[2*r+1].z, buf[2*r+1].w};
            #pragma unroll
            for (int e = 0; e < 8; ++e) {
                unsigned xb = __builtin_bit_cast(unsigned, xv[e]);
                fhi[r][e] = (short)(xb >> 16);
                float hf = __builtin_bit_cast(float, xb & 0xFFFF0000u);
                float lf = xv[e] - hf;
                flo[r][e] = (short)(__builtin_bit_cast(unsigned, lf) >> 16);
            }
        }
        // upper tiles -> direct global stores (C/D: row = q*4+reg, col = m)
        float* __restrict__ dst = out + (size_t)(s0 + k) * NPAIR;
        #pragma unroll
        for (int ti = 0; ti < 4; ++ti) {
            #pragma unroll
            for (int tj = ti; tj < 4; ++tj) {
                f32x4 c = {0.f, 0.f, 0.f, 0.f};
                c = __builtin_amdgcn_mfma_f32_16x16x32_bf16(fhi[ti], fhi[tj], c, 0, 0, 0);
                c = __builtin_amdgcn_mfma_f32_16x16x32_bf16(fhi[ti], flo[tj], c, 0, 0, 0);
                c = __builtin_amdgcn_mfma_f32_16x16x32_bf16(flo[ti], fhi[tj], c, 0, 0, 0);
                int j = tj * 16 + m;
                #pragma unroll
                for (int r = 0; r < 4; ++r) {
                    int i = ti * 16 + (q << 2) + r;
                    if (ti < tj || j > i) {
                        int p = ((i * (127 - i)) >> 1) + j - i - 1;
                        dst[p] = c[r];       // plain store: L2 write-combines
                    }
                }
            }
        }
    };

    PROCESS(bufA, 0);
    PROCESS(bufB, 1);
    // single implicit store drain at endpgm, amortized over SPW samples
}

extern "C" void kernel_launch(void* const* d_in, const int* in_sizes, int n_in,
                              void* d_out, int out_size, void* d_ws, size_t ws_size,
                              hipStream_t stream) {
    const float* in = (const float*)d_in[0];
    float* out = (float*)d_out;
    const int nsamples = in_sizes[0] / (NF * ND);   // 16384
    ip_gram_mfma<<<nsamples / (4 * SPW), 256, 0, stream>>>(in, out);
}

// Round 14
// 230.691 us; speedup vs baseline: 1.0603x; 1.0603x over previous
//
#include <hip/hip_runtime.h>

#define NF 64
#define ND 32
#define NPAIR 2016

typedef __attribute__((ext_vector_type(8))) short bf16x8;
typedef __attribute__((ext_vector_type(4))) float f32x4;

// EMPIRICAL BEST (R10: 81.3 us kernel / 232.9 us bench). Reverted to after
// R11 (pipelining) and R12 (load/store de-interleave) both regressed.
// Session ledger: six structural families (occ 27-70%, scatter/coalesced/NT
// stores, SPW 1-4, pipeline depth 1-2, load-first ordering) all land at
// 81-92 us; sample service rate invariant ~193/us => saturated shared
// memory-system resource not visible in SQ/TCC counters. Structure below:
// direct per-lane fragment loads (no input LDS), fp32->bf16 hi/lo 3-MFMA
// split, wave-private LDS output row, fully-coalesced dwordx4 epilogue
// (WRITE_SIZE == output exactly).
__global__ __launch_bounds__(256, 5) void ip_gram_mfma(
    const float* __restrict__ in, float* __restrict__ out) {

    __shared__ float obuf[4][NPAIR];   // 32256 B -> 5 blocks/CU; wave-private, no barriers

    const int t = threadIdx.x;
    const int w = t >> 6;
    const int l = t & 63;
    const int s = blockIdx.x * 4 + w;

    const int q = l >> 4;    // k-block: this lane covers k = 8q..8q+7
    const int m = l & 15;    // row within each 16-row block

    const float* src = in + (size_t)s * (NF * ND) + (q << 3);

    // ---- direct fragment load + fp32 -> bf16 hi/lo split (exact residual) ----
    bf16x8 fhi[4], flo[4];
    #pragma unroll
    for (int r = 0; r < 4; ++r) {
        const float* rowp = src + (r * 16 + m) * ND;
        float4 v0 = ((const float4*)rowp)[0];
        float4 v1 = ((const float4*)rowp)[1];
        float xv[8] = {v0.x, v0.y, v0.z, v0.w, v1.x, v1.y, v1.z, v1.w};
        #pragma unroll
        for (int e = 0; e < 8; ++e) {
            unsigned xb = __builtin_bit_cast(unsigned, xv[e]);
            fhi[r][e] = (short)(xb >> 16);                         // truncate -> hi
            float hf = __builtin_bit_cast(float, xb & 0xFFFF0000u);
            float lf = xv[e] - hf;                                 // exact residual
            flo[r][e] = (short)(__builtin_bit_cast(unsigned, lf) >> 16);
        }
    }

    // ---- upper tiles: D = Xhi*Xhi^T + Xhi*Xlo^T + Xlo*Xhi^T -> LDS row ----
    // Fragment serves as BOTH A and B (gram). C/D: row = q*4 + reg, col = m.
    float* __restrict__ ob = obuf[w];
    #pragma unroll
    for (int ti = 0; ti < 4; ++ti) {
        #pragma unroll
        for (int tj = ti; tj < 4; ++tj) {
            f32x4 c = {0.f, 0.f, 0.f, 0.f};
            c = __builtin_amdgcn_mfma_f32_16x16x32_bf16(fhi[ti], fhi[tj], c, 0, 0, 0);
            c = __builtin_amdgcn_mfma_f32_16x16x32_bf16(fhi[ti], flo[tj], c, 0, 0, 0);
            c = __builtin_amdgcn_mfma_f32_16x16x32_bf16(flo[ti], fhi[tj], c, 0, 0, 0);
            int j = tj * 16 + m;
            #pragma unroll
            for (int r = 0; r < 4; ++r) {
                int i = ti * 16 + (q << 2) + r;
                if (ti < tj || j > i) {
                    int p = ((i * (127 - i)) >> 1) + j - i - 1;
                    ob[p] = c[r];
                }
            }
        }
    }

    // ---- coalesced epilogue: contiguous 8064-B sample row, dwordx4 stores ----
    float4* __restrict__ dst4 = (float4*)(out + (size_t)s * NPAIR);  // 8064 = 504*16: 16B-aligned
    const float4* __restrict__ ob4 = (const float4*)ob;
    #pragma unroll
    for (int it = 0; it < 8; ++it) {
        int idx4 = l + (it << 6);
        if (idx4 < NPAIR / 4) {            // 504 float4s (last iter: 56/64 lanes)
            dst4[idx4] = ob4[idx4];
        }
    }
}

extern "C" void kernel_launch(void* const* d_in, const int* in_sizes, int n_in,
                              void* d_out, int out_size, void* d_ws, size_t ws_size,
                              hipStream_t stream) {
    const float* in = (const float*)d_in[0];
    float* out = (float*)d_out;
    const int nsamples = in_sizes[0] / (NF * ND);   // 16384
    ip_gram_mfma<<<nsamples / 4, 256, 0, stream>>>(in, out);
}

// Round 19
// 228.965 us; speedup vs baseline: 1.0683x; 1.0075x over previous
//
#include <hip/hip_runtime.h>

#define NF 64
#define ND 32
#define NPAIR 2016
#define KSTR 40                   // bf16 units per field row (80 B): b128-aligned, ~2-way banks
#define SAMP_BF (NF * KSTR)       // 2560 bf16 per (hi|lo) array per sample

typedef __attribute__((ext_vector_type(8))) short bf16x8;
typedef __attribute__((ext_vector_type(4))) float f32x4;

// Dense+dense cell of the read/write coalescing matrix (R14 post-mortem):
// R0's input path (lane-contiguous float4 loads -> hi/lo split -> LDS KSTR=40
// -> bf16x8 fragment reads) + R10's output path (LDS row -> dense dwordx4
// epilogue). Every global instruction on BOTH streams now touches fully-used
// cache lines, like the 6.3 TB/s copy ubench. Tests whether per-instruction
// line-splitting explains the session's half-of-copy-BW anomaly.
// 4 waves/block, one sample per wave, wave-private LDS regions, no barriers.
__global__ __launch_bounds__(256, 2) void ip_gram_mfma(
    const float* __restrict__ in, float* __restrict__ out) {

    __shared__ unsigned short sh[4 * 2 * SAMP_BF];   // 40960 B input staging
    __shared__ float obuf[4][NPAIR];                 // 32256 B output staging

    const int t = threadIdx.x;
    const int w = t >> 6;
    const int l = t & 63;
    const int s = blockIdx.x * 4 + w;

    unsigned short* __restrict__ xhi = sh + w * 2 * SAMP_BF;
    unsigned short* __restrict__ xlo = xhi + SAMP_BF;

    const float* src = in + (size_t)s * (NF * ND);

    // ---- stage: coalesced float4 loads (16 dense lines/instr), split hi/lo ----
    #pragma unroll
    for (int it = 0; it < 8; ++it) {
        int idx4 = l + (it << 6);           // float4 index 0..511
        float4 v = ((const float4*)src)[idx4];
        int f  = idx4 >> 3;                 // field
        int k0 = (idx4 & 7) << 2;           // k base (multiple of 4)
        float xv[4] = {v.x, v.y, v.z, v.w};
        ushort4 hv, lv;
        unsigned short* hp = (unsigned short*)&hv;
        unsigned short* lp = (unsigned short*)&lv;
        #pragma unroll
        for (int e = 0; e < 4; ++e) {
            unsigned xb = __builtin_bit_cast(unsigned, xv[e]);
            hp[e] = (unsigned short)(xb >> 16);                       // truncate -> hi
            float hf = __builtin_bit_cast(float, xb & 0xFFFF0000u);
            float lf = xv[e] - hf;                                     // exact residual
            lp[e] = (unsigned short)(__builtin_bit_cast(unsigned, lf) >> 16);
        }
        *(ushort4*)&xhi[f * KSTR + k0] = hv;   // 8-B aligned
        *(ushort4*)&xlo[f * KSTR + k0] = lv;
    }

    // ---- load MFMA fragments: blk r covers fields r*16..r*16+15 ----
    // lane element: X[r*16 + (l&15)][(l>>4)*8 .. +8] (serves as BOTH A and B)
    const int q = l >> 4;
    const int m = l & 15;
    bf16x8 fhi[4], flo[4];
    #pragma unroll
    for (int r = 0; r < 4; ++r) {
        int off = (r * 16 + m) * KSTR + (q << 3);
        fhi[r] = *(const bf16x8*)&xhi[off];
        flo[r] = *(const bf16x8*)&xlo[off];
    }

    // ---- upper tiles: D = Xhi*Xhi^T + Xhi*Xlo^T + Xlo*Xhi^T -> LDS row ----
    // C/D layout: row i-part = q*4 + reg, col j-part = m.
    float* __restrict__ ob = obuf[w];
    #pragma unroll
    for (int ti = 0; ti < 4; ++ti) {
        #pragma unroll
        for (int tj = ti; tj < 4; ++tj) {
            f32x4 c = {0.f, 0.f, 0.f, 0.f};
            c = __builtin_amdgcn_mfma_f32_16x16x32_bf16(fhi[ti], fhi[tj], c, 0, 0, 0);
            c = __builtin_amdgcn_mfma_f32_16x16x32_bf16(fhi[ti], flo[tj], c, 0, 0, 0);
            c = __builtin_amdgcn_mfma_f32_16x16x32_bf16(flo[ti], fhi[tj], c, 0, 0, 0);
            int j = tj * 16 + m;
            #pragma unroll
            for (int r = 0; r < 4; ++r) {
                int i = ti * 16 + (q << 2) + r;
                if (ti < tj || j > i) {
                    int p = ((i * (127 - i)) >> 1) + j - i - 1;
                    ob[p] = c[r];
                }
            }
        }
    }

    // ---- coalesced epilogue: contiguous 8064-B sample row, dwordx4 stores ----
    float4* __restrict__ dst4 = (float4*)(out + (size_t)s * NPAIR);  // 16B-aligned
    const float4* __restrict__ ob4 = (const float4*)ob;
    #pragma unroll
    for (int it = 0; it < 8; ++it) {
        int idx4 = l + (it << 6);
        if (idx4 < NPAIR / 4) {            // 504 float4s (last iter: 56/64 lanes)
            dst4[idx4] = ob4[idx4];
        }
    }
}

extern "C" void kernel_launch(void* const* d_in, const int* in_sizes, int n_in,
                              void* d_out, int out_size, void* d_ws, size_t ws_size,
                              hipStream_t stream) {
    const float* in = (const float*)d_in[0];
    float* out = (float*)d_out;
    const int nsamples = in_sizes[0] / (NF * ND);   // 16384
    ip_gram_mfma<<<nsamples / 4, 256, 0, stream>>>(in, out);
}